// Round 4
// baseline (225.302 us; speedup 1.0000x reference)
//
#include <hip/hip_runtime.h>
#include <hip/hip_bf16.h>

// Problem constants: BS=8, H=16, NUM_JOB=64, OPS_PER_JOB=32, DK=64, L=2048.
// Model reduces to 8192 independent causal-attention problems of 32 tok x 64
// dim with RoPE positions 0..31 reset per job. Output dtype: float32.
//
// R5: L3 working-set reduction. R0-R4 post-mortems: time pinned at 88-100us
// across occupancy 17-34%, in-flight 8-24KB/wave, 1-4 jobs/wave => Little's-law
// equilibrium vs LOADED latency. Working set 268MB vs 256MB L3 => cyclic-scan
// thrash (FETCH 98MB/iter = half the input re-fetched from HBM at ~900cy).
// Fix: nontemporal O stores (no L3 allocate) so the 201MB input fits L3 whole
// and read latency drops to L3-hit. R3's nt attempt fragmented (scalar 4B/lane
// nt stores -> 64B partial lines, WRITE 65.5->80MB); here O goes through the
// free V LDS buffer so each nt store instruction writes 4x contiguous 256B
// row-slices (full 128B lines, 1KB/instr).
// Kept from R4: glds V prefetch (unsinkable, 0 VGPR), f16 stride-40 P
// transpose, 2048x256 grid, launch_bounds(256,4).

typedef _Float16 h8 __attribute__((ext_vector_type(8)));
typedef float f4 __attribute__((ext_vector_type(4)));
typedef unsigned short us8 __attribute__((ext_vector_type(8)));

// ln(10000)/32: theta_i = exp(-i * this)
#define ROPE_LN_CONST 0.28782313662425575f

// O staging stride in floats: 68 (=64+4) so the 4 lg-groups' rows land on
// disjoint-or-2-way bank sets for both the dword writes and b128 reads.
#define OSTRIDE 68

__device__ __forceinline__ float bf2f(unsigned short u) {
    return __uint_as_float(((unsigned int)u) << 16);
}

template<bool ISBF>
__device__ __forceinline__ void run(
    const void* __restrict__ qp, const void* __restrict__ kp,
    const void* __restrict__ vp, float* __restrict__ outp,
    _Float16* __restrict__ myps, unsigned char* __restrict__ myv,
    const int lane, const int lg, const int ln,
    const int b, const int h, const int j)
{
    const size_t base = ((size_t)((b * 16 + h) * 2048 + j * 32)) * 64;

    // ---- issue Q/K raw loads (A-frag addressing: lane holds
    // M[row = ti*16+ln][k = lg*8+t], k-chunks c*32) ----
    us8 qrb[2][2], krb[2][2];        // bf16 raw
    f4  qrf[2][2][2], krf[2][2][2];  // f32 raw
#pragma unroll
    for (int ti = 0; ti < 2; ++ti) {
        const size_t roff = base + (size_t)(ti * 16 + ln) * 64;
#pragma unroll
        for (int c = 0; c < 2; ++c) {
            const size_t off = roff + c * 32 + lg * 8;
            if constexpr (ISBF) {
                qrb[ti][c] = *(const us8*)((const unsigned short*)qp + off);
                krb[ti][c] = *(const us8*)((const unsigned short*)kp + off);
            } else {
                const float* q = (const float*)qp + off;
                const float* k = (const float*)kp + off;
                qrf[ti][c][0] = *(const f4*)q;
                qrf[ti][c][1] = *(const f4*)(q + 4);
                krf[ti][c][0] = *(const f4*)k;
                krf[ti][c][1] = *(const f4*)(k + 4);
            }
        }
    }

    // ---- issue V -> LDS (global_load_lds width 16: wave-uniform LDS base +
    // lane*16, per-lane global addr). No dest reg => cannot be sunk; 0 VGPR.
    // LDS layout = linear row-major V[32][64], same as global. ----
    if constexpr (ISBF) {
#pragma unroll
        for (int i = 0; i < 4; ++i)   // 1KB/inst = 8 rows of 128B
            __builtin_amdgcn_global_load_lds(
                (const __attribute__((address_space(1))) void*)
                    ((const unsigned short*)vp + base + i * 512 + lane * 8),
                (__attribute__((address_space(3))) void*)(myv + i * 1024),
                16, 0, 0);
    } else {
#pragma unroll
        for (int i = 0; i < 8; ++i)   // 1KB/inst = 4 rows of 256B
            __builtin_amdgcn_global_load_lds(
                (const __attribute__((address_space(1))) void*)
                    ((const float*)vp + base + i * 256 + lane * 4),
                (__attribute__((address_space(3))) void*)(myv + i * 1024),
                16, 0, 0);
    }
    __builtin_amdgcn_sched_barrier(0);

    // ---- RoPE Q/K -> f16 frags (vmcnt waits cover Q/K only; V glds younger) ----
    h8 qf[2][2], kf[2][2];
#pragma unroll
    for (int ti = 0; ti < 2; ++ti) {
        const float r = (float)(ti * 16 + ln);   // token index = RoPE pos
#pragma unroll
        for (int c = 0; c < 2; ++c) {
            float qa[8], ka[8];
            if constexpr (ISBF) {
#pragma unroll
                for (int t = 0; t < 8; ++t) {
                    qa[t] = bf2f(qrb[ti][c][t]);
                    ka[t] = bf2f(krb[ti][c][t]);
                }
            } else {
#pragma unroll
                for (int t = 0; t < 8; ++t) {
                    qa[t] = qrf[ti][c][t >> 2][t & 3];
                    ka[t] = krf[ti][c][t >> 2][t & 3];
                }
            }
#pragma unroll
            for (int t = 0; t < 4; ++t) {
                const int i = ((c * 32 + lg * 8) >> 1) + t;   // pair idx 0..31
                const float th = __expf(-(float)i * ROPE_LN_CONST);
                float sn, cs;
                __sincosf(r * th, &sn, &cs);
                const float qe = qa[2 * t], qo = qa[2 * t + 1];
                const float ke = ka[2 * t], ko = ka[2 * t + 1];
                qf[ti][c][2 * t]     = (_Float16)(qe * cs - qo * sn);
                qf[ti][c][2 * t + 1] = (_Float16)(qo * cs + qe * sn);
                kf[ti][c][2 * t]     = (_Float16)(ke * cs - ko * sn);
                kf[ti][c][2 * t + 1] = (_Float16)(ko * cs + ke * sn);
            }
        }
    }

    // ---- S = Qr * Kr^T : 2x2 tiles of 16x16, K=64 in two chunks ----
    f4 sacc[2][2];
#pragma unroll
    for (int ti = 0; ti < 2; ++ti)
#pragma unroll
        for (int tj = 0; tj < 2; ++tj) {
            f4 acc = {0.f, 0.f, 0.f, 0.f};
            acc = __builtin_amdgcn_mfma_f32_16x16x32_f16(qf[ti][0], kf[tj][0], acc, 0, 0, 0);
            acc = __builtin_amdgcn_mfma_f32_16x16x32_f16(qf[ti][1], kf[tj][1], acc, 0, 0, 0);
            sacc[ti][tj] = acc;
        }

    // ---- causal softmax in C/D layout: row = ti*16+lg*4+reg, col = tj*16+ln ----
#pragma unroll
    for (int ti = 0; ti < 2; ++ti) {
#pragma unroll
        for (int reg = 0; reg < 4; ++reg) {
            const int row = ti * 16 + lg * 4 + reg;
            float s0 = sacc[ti][0][reg] * 0.125f;       // 1/sqrt(64)
            float s1 = sacc[ti][1][reg] * 0.125f;
            if (ln > row)      s0 = -INFINITY;
            if (16 + ln > row) s1 = -INFINITY;
            float m = fmaxf(s0, s1);
#pragma unroll
            for (int off = 8; off > 0; off >>= 1) m = fmaxf(m, __shfl_xor(m, off, 64));
            float p0 = __expf(s0 - m);                  // exp(-inf)=0 handles mask
            float p1 = __expf(s1 - m);
            float l = p0 + p1;
#pragma unroll
            for (int off = 8; off > 0; off >>= 1) l += __shfl_xor(l, off, 64);
            const float linv = 1.0f / l;
            sacc[ti][0][reg] = p0 * linv;               // fold 1/l into P
            sacc[ti][1][reg] = p1 * linv;
        }
    }

    // ---- transpose P: C/D layout -> A layout via wave-private LDS (f16) ----
#pragma unroll
    for (int ti = 0; ti < 2; ++ti)
#pragma unroll
        for (int tj = 0; tj < 2; ++tj)
#pragma unroll
            for (int reg = 0; reg < 4; ++reg)
                myps[(ti * 16 + lg * 4 + reg) * 40 + tj * 16 + ln] =
                    (_Float16)sacc[ti][tj][reg];

    // Wave-private buffer: wave-local ordering only (no barrier needed).
    asm volatile("s_waitcnt lgkmcnt(0)" ::: "memory");
    __builtin_amdgcn_sched_barrier(0);

    // A-frag read: row = ti*16+ln, k contiguous -> one b128 per tile.
    h8 paf[2];
#pragma unroll
    for (int ti = 0; ti < 2; ++ti)
        paf[ti] = *(const h8*)&myps[(ti * 16 + ln) * 40 + lg * 8];

    // ---- V frags from LDS (drain the global_load_lds first; by now the
    // ~24KB issued at the top has long returned) ----
    asm volatile("s_waitcnt vmcnt(0)" ::: "memory");
    __builtin_amdgcn_sched_barrier(0);

    // B-frag: vf[tj][t] = V[p = lg*8+t][d = tj*16+ln]
    h8 vf[4];
    if constexpr (ISBF) {
        const unsigned short* vh = (const unsigned short*)myv;
#pragma unroll
        for (int tj = 0; tj < 4; ++tj)
#pragma unroll
            for (int t = 0; t < 8; ++t)
                vf[tj][t] = (_Float16)bf2f(vh[(lg * 8 + t) * 64 + tj * 16 + ln]);
    } else {
        const float* vfp = (const float*)myv;
#pragma unroll
        for (int tj = 0; tj < 4; ++tj)
#pragma unroll
            for (int t = 0; t < 8; ++t)
                vf[tj][t] = (_Float16)vfp[(lg * 8 + t) * 64 + tj * 16 + ln];
    }
    // All V LDS reads must complete before we overwrite myv with O below.
    asm volatile("s_waitcnt lgkmcnt(0)" ::: "memory");
    __builtin_amdgcn_sched_barrier(0);

    // ---- O = P * V : 2x4 tiles into registers ----
    f4 oacc[2][4];
#pragma unroll
    for (int ti = 0; ti < 2; ++ti)
#pragma unroll
        for (int tj = 0; tj < 4; ++tj) {
            f4 acc = {0.f, 0.f, 0.f, 0.f};
            oacc[ti][tj] = __builtin_amdgcn_mfma_f32_16x16x32_f16(paf[ti], vf[tj], acc, 0, 0, 0);
        }

    // ---- O transpose through LDS (reuse myv): C/D layout -> row-major
    // [32][OSTRIDE] f32, so the global store is float4/lane = 4x contiguous
    // 256B row-slices (full 128B lines) per instruction -> nt-safe. ----
    float* ot = (float*)myv;
#pragma unroll
    for (int ti = 0; ti < 2; ++ti)
#pragma unroll
        for (int tj = 0; tj < 4; ++tj)
#pragma unroll
            for (int reg = 0; reg < 4; ++reg)
                ot[(ti * 16 + lg * 4 + reg) * OSTRIDE + tj * 16 + ln] =
                    oacc[ti][tj][reg];

    asm volatile("s_waitcnt lgkmcnt(0)" ::: "memory");
    __builtin_amdgcn_sched_barrier(0);

    // ---- nt store: out[b][s = j*32 + r][h*64 + 0..63], r = i*4 + lg,
    // lane covers 16B of one row; 1KB contiguous-per-row-slice per instr. ----
    const size_t obase = ((size_t)b * 2048 + j * 32) * 1024 + h * 64;
#pragma unroll
    for (int i = 0; i < 8; ++i) {
        const int r = i * 4 + lg;
        const f4 vrow = *(const f4*)&ot[r * OSTRIDE + ln * 4];
        f4* dst = (f4*)&outp[obase + (size_t)r * 1024 + ln * 4];
        __builtin_nontemporal_store(vrow, dst);
    }
}

__global__ __launch_bounds__(256, 4)
void attn_jobs(const void* __restrict__ qp, const void* __restrict__ kp,
               const void* __restrict__ vp, float* __restrict__ outp) {
    // Per-wave: P-transpose buffer (f16, stride 40) + V-staging/O-transpose
    // buffer (V: linear [32][64] raw for glds; O: [32][68] f32).
    // 4 x (2560 + 8704) = 45056 B -> 3 blocks/CU.
    __shared__ alignas(16) _Float16 ps[4][32 * 40];
    __shared__ alignas(16) unsigned char vbuf[4][32 * OSTRIDE * 4];

    const int tid  = threadIdx.x;
    const int wid  = tid >> 6;
    const int lane = tid & 63;
    const int lg   = lane >> 4;
    const int ln   = lane & 15;

    const int sub = blockIdx.x * 4 + wid;   // 0..8191
    const int j = sub & 63;
    const int h = (sub >> 6) & 15;
    const int b = sub >> 10;

    // ---- input dtype probe (wave-uniform): bf16 stream has bf16-exponent at
    // bits[14:7] of every dword; f32 stream has uniform mantissa bits there.
    unsigned int w0 = ((const unsigned int*)qp)[lane];
    unsigned int e8 = (w0 >> 7) & 0xFFu;
    bool hitb = (e8 >= 96u) && (e8 <= 144u);
    const bool isbf = (__popcll(__ballot(hitb)) >= 32);

    if (isbf) run<true >(qp, kp, vp, outp, ps[wid], vbuf[wid], lane, lg, ln, b, h, j);
    else      run<false>(qp, kp, vp, outp, ps[wid], vbuf[wid], lane, lg, ln, b, h, j);
}

extern "C" void kernel_launch(void* const* d_in, const int* in_sizes, int n_in,
                              void* d_out, int out_size, void* d_ws, size_t ws_size,
                              hipStream_t stream) {
    (void)in_sizes; (void)n_in; (void)d_ws; (void)ws_size; (void)out_size;
    const void* q = d_in[0];
    const void* k = d_in[1];
    const void* v = d_in[2];
    // d_in[3] (op_mapping) / d_in[4] (triu_mask) are deterministic constants;
    // their structure is baked into the kernel.
    attn_jobs<<<2048, 256, 0, stream>>>(q, k, v, (float*)d_out);
}

// Round 5
// 221.697 us; speedup vs baseline: 1.0163x; 1.0163x over previous
//
#include <hip/hip_runtime.h>
#include <hip/hip_bf16.h>

// Problem constants: BS=8, H=16, NUM_JOB=64, OPS_PER_JOB=32, DK=64, L=2048.
// Model reduces to 8192 independent causal-attention problems of 32 tok x 64
// dim with RoPE positions 0..31 reset per job. Output dtype: float32.
// Inputs are f32 (npz size 186MB = 3x64MB incompressible normals).
//
// R6: request-payload pass. R0-R5: time pinned 88-100us across occupancy
// 17-34%, in-flight 8-24KB/wave, 1-4 jobs/wave, nt stores (FETCH unmoved =>
// no L3 control from source). Requests-not-bytes Little's law fits all data:
// ~72 outstanding line-requests/CU x 375ns; copy ubench fills 128B/slot =
// 6.3TB/s, our f32 Q/K loads are 16B segments => ~64B avg payload = 3.1TB/s
// delivered (measured). Fix: K,V (2/3 of reads) become full-line 1KB/instr
// streams via global_load_lds with XOR-pre-swizzled source (granule32 ^=
// row&7 within each 1KB block: same 8 lines covered, lane-permuted only;
// read side applies the same XOR -> bank-spread frag reads). V LDS reused
// for P transpose. Q stays direct-to-reg. vmcnt(8) covers K+Q, V rides
// behind until vmcnt(0) at consumption.

typedef _Float16 h8 __attribute__((ext_vector_type(8)));
typedef float f4 __attribute__((ext_vector_type(4)));
typedef unsigned short us8 __attribute__((ext_vector_type(8)));

// ln(10000)/32: theta_i = exp(-i * this)
#define ROPE_LN_CONST 0.28782313662425575f

__device__ __forceinline__ float bf2f(unsigned short u) {
    return __uint_as_float(((unsigned int)u) << 16);
}

// ---------------- f32 input path (the live one) ----------------
__device__ __forceinline__ void run_f32(
    const float* __restrict__ qp, const float* __restrict__ kp,
    const float* __restrict__ vp, float* __restrict__ outp,
    float* __restrict__ kbuf, float* __restrict__ vbuf,   // 8KB each, per-wave
    const int lane, const int lg, const int ln,
    const int b, const int h, const int j)
{
    const size_t base = ((size_t)((b * 16 + h) * 2048 + j * 32)) * 64;

    // Swizzled glds staging, instr i covers rows 4i..4i+3 (1KB contiguous).
    // lane l: r4=l>>4, granule g=(l&15)>>1 (32B), half=l&1 (16B).
    // src float off = R*64 + (g^(R&7))*8 + half*4  => lds[R][g*32B+half*16B]
    // holds global granule g^(R&7). Permutation stays inside the 1KB block:
    // full-line requests preserved.
    const int r4 = lane >> 4, g = (lane & 15) >> 1, half = lane & 1;

    // ---- issue K stage (8 glds) ----
#pragma unroll
    for (int i = 0; i < 8; ++i) {
        const int R = i * 4 + r4;
        const size_t src = base + (size_t)R * 64 + ((g ^ (R & 7)) * 8) + half * 4;
        __builtin_amdgcn_global_load_lds(
            (const __attribute__((address_space(1))) void*)(kp + src),
            (__attribute__((address_space(3))) void*)((char*)kbuf + i * 1024),
            16, 0, 0);
    }
    __builtin_amdgcn_sched_barrier(0);

    // ---- issue Q direct-to-reg (A-frag rows; residual 16B-segment traffic) ----
    f4 qrf[2][2][2];
#pragma unroll
    for (int ti = 0; ti < 2; ++ti) {
        const size_t roff = base + (size_t)(ti * 16 + ln) * 64;
#pragma unroll
        for (int c = 0; c < 2; ++c) {
            const float* p = qp + roff + c * 32 + lg * 8;
            qrf[ti][c][0] = *(const f4*)p;
            qrf[ti][c][1] = *(const f4*)(p + 4);
        }
    }
    __builtin_amdgcn_sched_barrier(0);

    // ---- issue V stage (8 glds, same swizzle) — stays behind vmcnt(8) ----
#pragma unroll
    for (int i = 0; i < 8; ++i) {
        const int R = i * 4 + r4;
        const size_t src = base + (size_t)R * 64 + ((g ^ (R & 7)) * 8) + half * 4;
        __builtin_amdgcn_global_load_lds(
            (const __attribute__((address_space(1))) void*)(vp + src),
            (__attribute__((address_space(3))) void*)((char*)vbuf + i * 1024),
            16, 0, 0);
    }
    __builtin_amdgcn_sched_barrier(0);

    // K(8)+Q(8) done; V(8) still in flight.
    asm volatile("s_waitcnt vmcnt(8)" ::: "memory");
    __builtin_amdgcn_sched_barrier(0);

    // ---- K frags from swizzled LDS + RoPE both; A-frag: lane(ln,lg) holds
    // M[row=ti*16+ln][k=lg*8+t], k-chunks c*32 ----
    h8 qf[2][2], kf[2][2];
#pragma unroll
    for (int ti = 0; ti < 2; ++ti) {
        const int R = ti * 16 + ln;
        const float r = (float)R;               // token index = RoPE pos
#pragma unroll
        for (int c = 0; c < 2; ++c) {
            const int pos = (c * 4 + lg) ^ (R & 7);
            const float* kr = kbuf + R * 64 + pos * 8;
            const f4 k0 = *(const f4*)kr;
            const f4 k1 = *(const f4*)(kr + 4);
            float qa[8], ka[8];
#pragma unroll
            for (int t = 0; t < 8; ++t) {
                qa[t] = qrf[ti][c][t >> 2][t & 3];
                ka[t] = (t < 4) ? k0[t] : k1[t - 4];
            }
#pragma unroll
            for (int t = 0; t < 4; ++t) {
                const int i = ((c * 32 + lg * 8) >> 1) + t;   // pair idx 0..31
                const float th = __expf(-(float)i * ROPE_LN_CONST);
                float sn, cs;
                __sincosf(r * th, &sn, &cs);
                const float qe = qa[2 * t], qo = qa[2 * t + 1];
                const float ke = ka[2 * t], ko = ka[2 * t + 1];
                qf[ti][c][2 * t]     = (_Float16)(qe * cs - qo * sn);
                qf[ti][c][2 * t + 1] = (_Float16)(qo * cs + qe * sn);
                kf[ti][c][2 * t]     = (_Float16)(ke * cs - ko * sn);
                kf[ti][c][2 * t + 1] = (_Float16)(ko * cs + ke * sn);
            }
        }
    }

    // ---- S = Qr * Kr^T ----
    f4 sacc[2][2];
#pragma unroll
    for (int ti = 0; ti < 2; ++ti)
#pragma unroll
        for (int tj = 0; tj < 2; ++tj) {
            f4 acc = {0.f, 0.f, 0.f, 0.f};
            acc = __builtin_amdgcn_mfma_f32_16x16x32_f16(qf[ti][0], kf[tj][0], acc, 0, 0, 0);
            acc = __builtin_amdgcn_mfma_f32_16x16x32_f16(qf[ti][1], kf[tj][1], acc, 0, 0, 0);
            sacc[ti][tj] = acc;
        }

    // ---- causal softmax in C/D layout: row=ti*16+lg*4+reg, col=tj*16+ln ----
#pragma unroll
    for (int ti = 0; ti < 2; ++ti) {
#pragma unroll
        for (int reg = 0; reg < 4; ++reg) {
            const int row = ti * 16 + lg * 4 + reg;
            float s0 = sacc[ti][0][reg] * 0.125f;       // 1/sqrt(64)
            float s1 = sacc[ti][1][reg] * 0.125f;
            if (ln > row)      s0 = -INFINITY;
            if (16 + ln > row) s1 = -INFINITY;
            float m = fmaxf(s0, s1);
#pragma unroll
            for (int off = 8; off > 0; off >>= 1) m = fmaxf(m, __shfl_xor(m, off, 64));
            float p0 = __expf(s0 - m);
            float p1 = __expf(s1 - m);
            float l = p0 + p1;
#pragma unroll
            for (int off = 8; off > 0; off >>= 1) l += __shfl_xor(l, off, 64);
            const float linv = 1.0f / l;
            sacc[ti][0][reg] = p0 * linv;               // fold 1/l into P
            sacc[ti][1][reg] = p1 * linv;
        }
    }

    // ---- V frags: drain glds, read with swizzle-adjusted addressing.
    // vf[tj][t2] = V[p=lg*8+t2][d=tj*16+ln]; granule (d>>3)^(p&7). ----
    asm volatile("s_waitcnt vmcnt(0)" ::: "memory");
    __builtin_amdgcn_sched_barrier(0);
    h8 vf[4];
#pragma unroll
    for (int tj = 0; tj < 4; ++tj)
#pragma unroll
        for (int t2 = 0; t2 < 8; ++t2) {
            const int p = lg * 8 + t2;
            const int d = tj * 16 + ln;
            const int pos = (d >> 3) ^ (p & 7);
            vf[tj][t2] = (_Float16)vbuf[p * 64 + pos * 8 + (d & 7)];
        }
    // V reads must land before we overwrite vbuf with P below.
    asm volatile("s_waitcnt lgkmcnt(0)" ::: "memory");
    __builtin_amdgcn_sched_barrier(0);

    // ---- transpose P: C/D -> A layout via vbuf reused as f16, stride 40 ----
    _Float16* pbuf = (_Float16*)vbuf;
#pragma unroll
    for (int ti = 0; ti < 2; ++ti)
#pragma unroll
        for (int tj = 0; tj < 2; ++tj)
#pragma unroll
            for (int reg = 0; reg < 4; ++reg)
                pbuf[(ti * 16 + lg * 4 + reg) * 40 + tj * 16 + ln] =
                    (_Float16)sacc[ti][tj][reg];

    asm volatile("s_waitcnt lgkmcnt(0)" ::: "memory");
    __builtin_amdgcn_sched_barrier(0);

    h8 paf[2];
#pragma unroll
    for (int ti = 0; ti < 2; ++ti)
        paf[ti] = *(const h8*)&pbuf[(ti * 16 + ln) * 40 + lg * 8];

    // ---- O = P * V, store fused (plain f32 scalar stores; WRITE_SIZE was
    // already at the 65.5MB logical minimum with this pattern) ----
#pragma unroll
    for (int ti = 0; ti < 2; ++ti) {
#pragma unroll
        for (int tj = 0; tj < 4; ++tj) {
            f4 acc = {0.f, 0.f, 0.f, 0.f};
            acc = __builtin_amdgcn_mfma_f32_16x16x32_f16(paf[ti], vf[tj], acc, 0, 0, 0);
#pragma unroll
            for (int reg = 0; reg < 4; ++reg) {
                const int row = ti * 16 + lg * 4 + reg;
                outp[((size_t)b * 2048 + j * 32 + row) * 1024 + h * 64 + tj * 16 + ln] =
                    acc[reg];
            }
        }
    }
}

// ---------------- bf16 input path (fallback; R4 structure) ----------------
__device__ __forceinline__ void run_bf16(
    const unsigned short* __restrict__ qp, const unsigned short* __restrict__ kp,
    const unsigned short* __restrict__ vp, float* __restrict__ outp,
    float* __restrict__ kbuf, float* __restrict__ vbuf,
    const int lane, const int lg, const int ln,
    const int b, const int h, const int j)
{
    const size_t base = ((size_t)((b * 16 + h) * 2048 + j * 32)) * 64;

    us8 qrb[2][2], krb[2][2];
#pragma unroll
    for (int ti = 0; ti < 2; ++ti) {
        const size_t roff = base + (size_t)(ti * 16 + ln) * 64;
#pragma unroll
        for (int c = 0; c < 2; ++c) {
            const size_t off = roff + c * 32 + lg * 8;
            qrb[ti][c] = *(const us8*)(qp + off);
            krb[ti][c] = *(const us8*)(kp + off);
        }
    }
    // V -> LDS linear [32][128B] (4KB) into vbuf
    unsigned char* myv = (unsigned char*)vbuf;
#pragma unroll
    for (int i = 0; i < 4; ++i)
        __builtin_amdgcn_global_load_lds(
            (const __attribute__((address_space(1))) void*)(vp + base + i * 512 + lane * 8),
            (__attribute__((address_space(3))) void*)(myv + i * 1024),
            16, 0, 0);
    __builtin_amdgcn_sched_barrier(0);

    h8 qf[2][2], kf[2][2];
#pragma unroll
    for (int ti = 0; ti < 2; ++ti) {
        const float r = (float)(ti * 16 + ln);
#pragma unroll
        for (int c = 0; c < 2; ++c) {
            float qa[8], ka[8];
#pragma unroll
            for (int t = 0; t < 8; ++t) {
                qa[t] = bf2f(qrb[ti][c][t]);
                ka[t] = bf2f(krb[ti][c][t]);
            }
#pragma unroll
            for (int t = 0; t < 4; ++t) {
                const int i = ((c * 32 + lg * 8) >> 1) + t;
                const float th = __expf(-(float)i * ROPE_LN_CONST);
                float sn, cs;
                __sincosf(r * th, &sn, &cs);
                const float qe = qa[2 * t], qo = qa[2 * t + 1];
                const float ke = ka[2 * t], ko = ka[2 * t + 1];
                qf[ti][c][2 * t]     = (_Float16)(qe * cs - qo * sn);
                qf[ti][c][2 * t + 1] = (_Float16)(qo * cs + qe * sn);
                kf[ti][c][2 * t]     = (_Float16)(ke * cs - ko * sn);
                kf[ti][c][2 * t + 1] = (_Float16)(ko * cs + ke * sn);
            }
        }
    }

    f4 sacc[2][2];
#pragma unroll
    for (int ti = 0; ti < 2; ++ti)
#pragma unroll
        for (int tj = 0; tj < 2; ++tj) {
            f4 acc = {0.f, 0.f, 0.f, 0.f};
            acc = __builtin_amdgcn_mfma_f32_16x16x32_f16(qf[ti][0], kf[tj][0], acc, 0, 0, 0);
            acc = __builtin_amdgcn_mfma_f32_16x16x32_f16(qf[ti][1], kf[tj][1], acc, 0, 0, 0);
            sacc[ti][tj] = acc;
        }

#pragma unroll
    for (int ti = 0; ti < 2; ++ti) {
#pragma unroll
        for (int reg = 0; reg < 4; ++reg) {
            const int row = ti * 16 + lg * 4 + reg;
            float s0 = sacc[ti][0][reg] * 0.125f;
            float s1 = sacc[ti][1][reg] * 0.125f;
            if (ln > row)      s0 = -INFINITY;
            if (16 + ln > row) s1 = -INFINITY;
            float m = fmaxf(s0, s1);
#pragma unroll
            for (int off = 8; off > 0; off >>= 1) m = fmaxf(m, __shfl_xor(m, off, 64));
            float p0 = __expf(s0 - m);
            float p1 = __expf(s1 - m);
            float l = p0 + p1;
#pragma unroll
            for (int off = 8; off > 0; off >>= 1) l += __shfl_xor(l, off, 64);
            const float linv = 1.0f / l;
            sacc[ti][0][reg] = p0 * linv;
            sacc[ti][1][reg] = p1 * linv;
        }
    }

    // P transpose in kbuf (f16 stride 40)
    _Float16* myps = (_Float16*)kbuf;
#pragma unroll
    for (int ti = 0; ti < 2; ++ti)
#pragma unroll
        for (int tj = 0; tj < 2; ++tj)
#pragma unroll
            for (int reg = 0; reg < 4; ++reg)
                myps[(ti * 16 + lg * 4 + reg) * 40 + tj * 16 + ln] =
                    (_Float16)sacc[ti][tj][reg];

    asm volatile("s_waitcnt lgkmcnt(0)" ::: "memory");
    __builtin_amdgcn_sched_barrier(0);

    h8 paf[2];
#pragma unroll
    for (int ti = 0; ti < 2; ++ti)
        paf[ti] = *(const h8*)&myps[(ti * 16 + ln) * 40 + lg * 8];

    asm volatile("s_waitcnt vmcnt(0)" ::: "memory");
    __builtin_amdgcn_sched_barrier(0);

    h8 vf[4];
    const unsigned short* vh = (const unsigned short*)myv;
#pragma unroll
    for (int tj = 0; tj < 4; ++tj)
#pragma unroll
        for (int t = 0; t < 8; ++t)
            vf[tj][t] = (_Float16)bf2f(vh[(lg * 8 + t) * 64 + tj * 16 + ln]);

#pragma unroll
    for (int ti = 0; ti < 2; ++ti) {
#pragma unroll
        for (int tj = 0; tj < 4; ++tj) {
            f4 acc = {0.f, 0.f, 0.f, 0.f};
            acc = __builtin_amdgcn_mfma_f32_16x16x32_f16(paf[ti], vf[tj], acc, 0, 0, 0);
#pragma unroll
            for (int reg = 0; reg < 4; ++reg) {
                const int row = ti * 16 + lg * 4 + reg;
                outp[((size_t)b * 2048 + j * 32 + row) * 1024 + h * 64 + tj * 16 + ln] =
                    acc[reg];
            }
        }
    }
}

__global__ __launch_bounds__(256, 2)
void attn_jobs(const void* __restrict__ qp, const void* __restrict__ kp,
               const void* __restrict__ vp, float* __restrict__ outp) {
    // Per-wave: kbuf 8KB + vbuf 8KB (vbuf reused for P transpose).
    // 4 waves x 16KB = 64KB -> 2 blocks/CU (8 waves/CU; R3/R5 showed the
    // 17-34% occupancy band is not first-order).
    __shared__ alignas(16) float kv[4][2][2048];

    const int tid  = threadIdx.x;
    const int wid  = tid >> 6;
    const int lane = tid & 63;
    const int lg   = lane >> 4;
    const int ln   = lane & 15;

    const int sub = blockIdx.x * 4 + wid;   // 0..8191
    const int j = sub & 63;
    const int h = (sub >> 6) & 15;
    const int b = sub >> 10;

    // ---- input dtype probe (wave-uniform): bf16 stream has bf16-exponent at
    // bits[14:7] of every dword; f32 stream has uniform mantissa bits there.
    unsigned int w0 = ((const unsigned int*)qp)[lane];
    unsigned int e8 = (w0 >> 7) & 0xFFu;
    bool hitb = (e8 >= 96u) && (e8 <= 144u);
    const bool isbf = (__popcll(__ballot(hitb)) >= 32);

    if (isbf)
        run_bf16((const unsigned short*)qp, (const unsigned short*)kp,
                 (const unsigned short*)vp, (float*)outp,
                 kv[wid][0], kv[wid][1], lane, lg, ln, b, h, j);
    else
        run_f32((const float*)qp, (const float*)kp, (const float*)vp,
                (float*)outp, kv[wid][0], kv[wid][1], lane, lg, ln, b, h, j);
}

extern "C" void kernel_launch(void* const* d_in, const int* in_sizes, int n_in,
                              void* d_out, int out_size, void* d_ws, size_t ws_size,
                              hipStream_t stream) {
    (void)in_sizes; (void)n_in; (void)d_ws; (void)ws_size; (void)out_size;
    const void* q = d_in[0];
    const void* k = d_in[1];
    const void* v = d_in[2];
    // d_in[3] (op_mapping) / d_in[4] (triu_mask) are deterministic constants;
    // their structure is baked into the kernel.
    attn_jobs<<<2048, 256, 0, stream>>>(q, k, v, (float*)d_out);
}